// Round 7
// baseline (896.792 us; speedup 1.0000x reference)
//
#include <hip/hip_runtime.h>

// GCN 3-layer (PyG GCNConv: self-loops + D^-1/2 A D^-1/2).
// R7: (a) batch-16 GEMM per wave -> W L1 traffic /16 (R5/R6 were bound by
// 16KB/node W re-reads through L1: 256cyc/node = 41us/CU); (b) wave-uniform
// CSR walk: readfirstlane(rowptr), uniform col[j] loads -> zero bpermutes,
// zero masking, all 64 lanes gather hw[c*64+lane] coalesced; (c) fp32
// features again (no unpack VALU, absmax back to ~2e-4).

#define SHIFT 9
#define BW_ (1 << SHIFT)      // 512 nodes per bucket
#define ITEMS 16              // edges per thread in k_partition
#define AB 16                 // nodes per wave batch in k_agg_gemm64

__global__ __launch_bounds__(256) void k_partition(
    const int* __restrict__ src, const int* __restrict__ dst, int E,
    int* __restrict__ bcur, unsigned* __restrict__ words, int cap) {
    __shared__ int cnt[256];
    __shared__ int gbase[256];
    int t = threadIdx.x;
    int base = blockIdx.x * (256 * ITEMS);
    cnt[t] = 0;
    __syncthreads();
    unsigned w[ITEMS]; int b[ITEMS], r[ITEMS];
    #pragma unroll
    for (int j = 0; j < ITEMS; ++j) {
        int e = base + j * 256 + t;
        if (e < E) {
            int d = dst[e], s = src[e];
            b[j] = d >> SHIFT;
            w[j] = ((unsigned)s << SHIFT) | (unsigned)(d & (BW_ - 1));
            r[j] = atomicAdd(&cnt[b[j]], 1);     // LDS atomic
        } else b[j] = -1;
    }
    __syncthreads();
    int c = cnt[t];
    gbase[t] = c ? atomicAdd(&bcur[t], c) : 0;
    __syncthreads();
    #pragma unroll
    for (int j = 0; j < ITEMS; ++j) {
        if (b[j] >= 0) {
            int idx = gbase[b[j]] + r[j];
            if (idx < cap)
                words[(size_t)b[j] * cap + idx] = w[j];
        }
    }
}

__global__ __launch_bounds__(512) void k_hist(
    const unsigned* __restrict__ words, const int* __restrict__ bcnt, int cap,
    int* __restrict__ deg, int N) {
    __shared__ int h[BW_];
    int b = blockIdx.x, t = threadIdx.x;
    h[t] = 0;
    __syncthreads();
    int n = min(bcnt[b], cap);
    const unsigned* wb = words + (size_t)b * cap;
    for (int i = t; i < n; i += 512)
        atomicAdd(&h[wb[i] & (BW_ - 1)], 1);
    __syncthreads();
    int node = b * BW_ + t;
    if (node < N) deg[node] = h[t];
}

__global__ __launch_bounds__(512) void k_place(
    const unsigned* __restrict__ words, const int* __restrict__ bcnt, int cap,
    const int* __restrict__ rowptr, int* __restrict__ col, int N) {
    __shared__ int cur[BW_];
    int b = blockIdx.x, t = threadIdx.x;
    int node = b * BW_ + t;
    cur[t] = (node < N) ? rowptr[node] : 0;
    __syncthreads();
    int n = min(bcnt[b], cap);
    const unsigned* wb = words + (size_t)b * cap;
    for (int i = t; i < n; i += 512) {
        unsigned w = wb[i];
        int p = atomicAdd(&cur[w & (BW_ - 1)], 1);
        col[p] = (int)(w >> SHIFT);
    }
}

__global__ void k_scan1(const int* __restrict__ deg, int N,
                        int* __restrict__ rowptr, int* __restrict__ bsum) {
    __shared__ int lds[256];
    int t = threadIdx.x;
    int i = blockIdx.x * 256 + t;
    int v = (i < N) ? deg[i] : 0;
    lds[t] = v; __syncthreads();
    #pragma unroll
    for (int off = 1; off < 256; off <<= 1) {
        int tmp = (t >= off) ? lds[t - off] : 0; __syncthreads();
        lds[t] += tmp; __syncthreads();
    }
    if (i < N) rowptr[i] = lds[t] - v;
    if (t == 255) bsum[blockIdx.x] = lds[255];
}

__global__ void k_scan2(const int* __restrict__ bsum, int nb, int* __restrict__ boff) {
    __shared__ int lds[1024];
    int t = threadIdx.x;
    int v = (t < nb) ? bsum[t] : 0;
    lds[t] = v; __syncthreads();
    #pragma unroll
    for (int off = 1; off < 1024; off <<= 1) {
        int tmp = (t >= off) ? lds[t - off] : 0; __syncthreads();
        lds[t] += tmp; __syncthreads();
    }
    if (t < nb) boff[t] = lds[t] - v;
    if (t == 0) boff[nb] = lds[1023];
}

__global__ void k_scan3(const int* __restrict__ boff, int N, int nb,
                        int* __restrict__ rowptr, const int* __restrict__ deg,
                        float* __restrict__ dinv) {
    int i = blockIdx.x * blockDim.x + threadIdx.x;
    if (i < N) {
        rowptr[i] += boff[i >> 8];
        dinv[i] = rsqrtf((float)deg[i] + 1.0f);
    } else if (i == N) {
        rowptr[N] = boff[nb];
    }
}

// hw1[n,d] = dinv[n]*(x[n]*W1[0,d] + c[d])  (fp32)
__global__ void k_layer1(const float* __restrict__ x, const float* __restrict__ delta,
                         const float* __restrict__ W1, const float* __restrict__ dinv,
                         float* __restrict__ hw, int N) {
    int idx = blockIdx.x * blockDim.x + threadIdx.x;
    if (idx >= N * 64) return;
    int n = idx >> 6, d = idx & 63;
    float c = delta[0] * W1[64 + d] + delta[1] * W1[128 + d] +
              delta[2] * W1[192 + d] + delta[3] * W1[256 + d];
    hw[idx] = dinv[n] * fmaf(x[n], W1[d], c);
}

// Wave-uniform gather: bounds/indices via readfirstlane (SGPR), all 64 lanes
// load one 256B row per edge. Zero cross-lane ops, zero divergence.
__device__ __forceinline__ float agg_row_u(const float* __restrict__ hw,
                                           const int* __restrict__ col,
                                           int rs, int re, int lane, float acc) {
    int j = rs;
    for (; j + 8 <= re; j += 8) {                  // 8 gathers in flight
        int c0 = __builtin_amdgcn_readfirstlane(col[j + 0]);
        int c1 = __builtin_amdgcn_readfirstlane(col[j + 1]);
        int c2 = __builtin_amdgcn_readfirstlane(col[j + 2]);
        int c3 = __builtin_amdgcn_readfirstlane(col[j + 3]);
        int c4 = __builtin_amdgcn_readfirstlane(col[j + 4]);
        int c5 = __builtin_amdgcn_readfirstlane(col[j + 5]);
        int c6 = __builtin_amdgcn_readfirstlane(col[j + 6]);
        int c7 = __builtin_amdgcn_readfirstlane(col[j + 7]);
        float v0 = hw[(size_t)c0 * 64 + lane];
        float v1 = hw[(size_t)c1 * 64 + lane];
        float v2 = hw[(size_t)c2 * 64 + lane];
        float v3 = hw[(size_t)c3 * 64 + lane];
        float v4 = hw[(size_t)c4 * 64 + lane];
        float v5 = hw[(size_t)c5 * 64 + lane];
        float v6 = hw[(size_t)c6 * 64 + lane];
        float v7 = hw[(size_t)c7 * 64 + lane];
        acc += ((v0 + v1) + (v2 + v3)) + ((v4 + v5) + (v6 + v7));
    }
    for (; j < re; ++j) {
        int c = __builtin_amdgcn_readfirstlane(col[j]);
        acc += hw[(size_t)c * 64 + lane];
    }
    return acc;
}

// Aggregate AB=16 nodes into LDS, then ONE batched GEMM: W read once per wave
// (16KB L1 traffic amortized over 16 nodes instead of per node).
__global__ __launch_bounds__(256) void k_agg_gemm64(
    const float* __restrict__ hw_in, const int* __restrict__ rowptr,
    const int* __restrict__ col, const float* __restrict__ dinv,
    const float* __restrict__ bias, const float* __restrict__ W,
    float* __restrict__ hw_out, int N) {
    __shared__ float tbuf[4][AB][64];
    int lane = threadIdx.x & 63, wave = threadIdx.x >> 6;
    float b = bias[lane];
    int base = (blockIdx.x * 4 + wave) * AB;
    if (base >= N) return;
    int cnt = min(AB, N - base);
    for (int m = 0; m < cnt; ++m) {              // aggregation phase
        int nu = __builtin_amdgcn_readfirstlane(base + m);
        int rs = __builtin_amdgcn_readfirstlane(rowptr[nu]);
        int re = __builtin_amdgcn_readfirstlane(rowptr[nu + 1]);
        float acc = hw_in[(size_t)nu * 64 + lane];          // self-loop
        acc = agg_row_u(hw_in, col, rs, re, lane, acc);
        tbuf[wave][m][lane] = fmaxf(fmaf(dinv[nu], acc, b), 0.0f);
    }
    __builtin_amdgcn_wave_barrier();
    float o[AB];                                 // GEMM phase: o[m] += t[m][k]*W[k][lane]
    #pragma unroll
    for (int m = 0; m < AB; ++m) o[m] = 0.f;
    const float4* tb = (const float4*)&tbuf[wave][0][0];   // [m][k4]
    #pragma unroll
    for (int k4 = 0; k4 < 16; ++k4) {
        float w0 = W[(4 * k4 + 0) * 64 + lane];  // 4 L1 loads per k4, /16 nodes
        float w1 = W[(4 * k4 + 1) * 64 + lane];
        float w2 = W[(4 * k4 + 2) * 64 + lane];
        float w3 = W[(4 * k4 + 3) * 64 + lane];
        #pragma unroll
        for (int m = 0; m < AB; ++m) {
            float4 tv = tb[m * 16 + k4];         // broadcast ds_read_b128
            o[m] = fmaf(tv.x, w0, o[m]);
            o[m] = fmaf(tv.y, w1, o[m]);
            o[m] = fmaf(tv.z, w2, o[m]);
            o[m] = fmaf(tv.w, w3, o[m]);
        }
    }
    #pragma unroll
    for (int m = 0; m < AB; ++m) {
        if (m < cnt)
            hw_out[(size_t)(base + m) * 64 + lane] = dinv[base + m] * o[m];
    }
}

__global__ __launch_bounds__(256) void k_agg_out3(
    const float* __restrict__ hw_in, const int* __restrict__ rowptr,
    const int* __restrict__ col, const float* __restrict__ dinv,
    const float* __restrict__ bias, const float* __restrict__ W3,
    float4* __restrict__ hw3, int N) {
    int lane = threadIdx.x & 63, wave = threadIdx.x >> 6;
    float w0 = W3[lane * 3 + 0], w1 = W3[lane * 3 + 1], w2 = W3[lane * 3 + 2];
    float b = bias[lane];
    int nw = gridDim.x * 4;
    int gw = blockIdx.x * 4 + wave;
    int npw = (N + nw - 1) / nw;                 // contiguous node range per wave
    int n0 = gw * npw, n1 = min(N, n0 + npw);
    for (int n = n0; n < n1; ++n) {
        int nu = __builtin_amdgcn_readfirstlane(n);
        int rs = __builtin_amdgcn_readfirstlane(rowptr[nu]);
        int re = __builtin_amdgcn_readfirstlane(rowptr[nu + 1]);
        float acc = hw_in[(size_t)nu * 64 + lane];
        acc = agg_row_u(hw_in, col, rs, re, lane, acc);
        float dn = dinv[nu];
        float t = fmaxf(fmaf(dn, acc, b), 0.0f);
        float p0 = t * w0, p1 = t * w1, p2 = t * w2;
        #pragma unroll
        for (int off = 32; off; off >>= 1) {
            p0 += __shfl_xor(p0, off);
            p1 += __shfl_xor(p1, off);
            p2 += __shfl_xor(p2, off);
        }
        if (lane == 0) hw3[nu] = make_float4(dn * p0, dn * p1, dn * p2, 0.f);
    }
}

__global__ __launch_bounds__(256) void k_final(
    const float4* __restrict__ hw3, const int* __restrict__ rowptr,
    const int* __restrict__ col, const float* __restrict__ dinv,
    const float* __restrict__ b3, const float* __restrict__ x,
    const float* __restrict__ pos, float* __restrict__ out, int N) {
    int lane = threadIdx.x & 63, wave = threadIdx.x >> 6;
    int n = blockIdx.x * 4 + wave;
    if (n >= N) return;
    int rs = rowptr[n], re = rowptr[n + 1];
    float a0 = 0.f, a1 = 0.f, a2 = 0.f;
    for (int i = rs + lane; i < re; i += 64) {
        float4 v = hw3[col[i]];
        a0 += v.x; a1 += v.y; a2 += v.z;
    }
    #pragma unroll
    for (int off = 32; off; off >>= 1) {
        a0 += __shfl_xor(a0, off);
        a1 += __shfl_xor(a1, off);
        a2 += __shfl_xor(a2, off);
    }
    if (lane == 0) {
        float4 sv = hw3[n];
        a0 += sv.x; a1 += sv.y; a2 += sv.z;
        float dn = dinv[n];
        float o0 = fmaf(dn, a0, b3[0]);
        float o1 = fmaf(dn, a1, b3[1]);
        float o2 = fmaf(dn, a2, b3[2]);
        out[n] = x[n] + o2;
        out[N + 2 * n]     = pos[2 * n]     + o0;
        out[N + 2 * n + 1] = pos[2 * n + 1] + o1;
    }
}

extern "C" void kernel_launch(void* const* d_in, const int* in_sizes, int n_in,
                              void* d_out, int out_size, void* d_ws, size_t ws_size,
                              hipStream_t stream) {
    const float* x     = (const float*)d_in[0];
    const float* pos   = (const float*)d_in[1];
    const float* delta = (const float*)d_in[2];
    const int*   ei    = (const int*)  d_in[3];
    const float* W1    = (const float*)d_in[4];
    const float* b1    = (const float*)d_in[5];
    const float* W2    = (const float*)d_in[6];
    const float* b2    = (const float*)d_in[7];
    const float* W3    = (const float*)d_in[8];
    const float* b3    = (const float*)d_in[9];
    int N = in_sizes[0];
    int E = in_sizes[3] / 2;
    const int* src = ei;
    const int* dst = ei + E;

    char* p = (char*)d_ws;
    auto alloc = [&](size_t bytes) {
        char* r = p; p += (bytes + 255) & ~(size_t)255; return r;
    };
    int*   deg    = (int*)  alloc((size_t)N * 4);
    int*   bcur   = (int*)  alloc(256 * 4);
    int*   rowptr = (int*)  alloc((size_t)(N + 1) * 4);
    int nb1 = (N + 255) / 256;
    int*   bsum   = (int*)  alloc((size_t)nb1 * 4);
    int*   boff   = (int*)  alloc((size_t)(nb1 + 1) * 4);
    float* dinv   = (float*)alloc((size_t)N * 4);
    int*   col    = (int*)  alloc((size_t)E * 4);
    float* hw_a   = (float*)alloc((size_t)N * 64 * 4);   // fp32 features
    float* hw_b   = (float*)alloc((size_t)N * 64 * 4);

    int B   = (N + BW_ - 1) >> SHIFT;   // 196 buckets for N=100K
    int cap = 2 * (E / B) + 1024;
    unsigned* words = (unsigned*)hw_b;  // hw_b dead until agg_gemm64 (13.7MB<25.6)
    float4*   hw3   = (float4*)hw_a;    // hw_a dead after agg_out3 consumes hw_b

    int npb = (E + (256 * ITEMS) - 1) / (256 * ITEMS);

    hipMemsetAsync(bcur, 0, 256 * 4, stream);
    k_partition<<<npb, 256, 0, stream>>>(src, dst, E, bcur, words, cap);
    k_hist<<<B, 512, 0, stream>>>(words, bcur, cap, deg, N);
    k_scan1<<<nb1, 256, 0, stream>>>(deg, N, rowptr, bsum);
    k_scan2<<<1, 1024, 0, stream>>>(bsum, nb1, boff);
    k_scan3<<<(N + 256) / 256, 256, 0, stream>>>(boff, N, nb1, rowptr, deg, dinv);
    k_place<<<B, 512, 0, stream>>>(words, bcur, cap, rowptr, col, N);
    k_layer1<<<(N * 64 + 255) / 256, 256, 0, stream>>>(x, delta, W1, dinv, hw_a, N);
    k_agg_gemm64<<<(N + 4 * AB - 1) / (4 * AB), 256, 0, stream>>>(
        hw_a, rowptr, col, dinv, b1, W2, hw_b, N);
    k_agg_out3<<<2048, 256, 0, stream>>>(hw_b, rowptr, col, dinv, b2, W3, hw3, N);
    k_final<<<(N + 3) / 4, 256, 0, stream>>>(hw3, rowptr, col, dinv, b3, x, pos,
                                             (float*)d_out, N);
}

// Round 9
// 298.358 us; speedup vs baseline: 3.0058x; 3.0058x over previous
//
#include <hip/hip_runtime.h>

// GCN 3-layer (PyG GCNConv: self-loops + D^-1/2 A D^-1/2).
// R8 (resubmitted R9 after acquisition timeout): de-fuse. R7's batched fused
// GEMM blew VGPR(256)/LDS -> occupancy 7%. Now: k_agg1 = R6's proven bf16
// gather (68us fused) MINUS the GEMM phase; k_gemm64 = separate dense
// hw2=dinv*(h2@W2), 8 nodes/wave register-blocked, row broadcast via literal
// v_readlane (VGPR ~35, W L1 traffic /8); k_agg2 = R6 agg_out3 unchanged.

#define SHIFT 9
#define BW_ (1 << SHIFT)      // 512 nodes per bucket
#define ITEMS 16              // edges per thread in k_partition

__device__ __forceinline__ float blo(unsigned w) { return __uint_as_float(w << 16); }
__device__ __forceinline__ float bhi(unsigned w) { return __uint_as_float(w & 0xffff0000u); }
__device__ __forceinline__ unsigned packbf(float a, float b) {
    unsigned ua = __float_as_uint(a), ub = __float_as_uint(b);
    ua = (ua + 0x7fffu + ((ua >> 16) & 1u)) >> 16;         // RN-even
    ub = (ub + 0x7fffu + ((ub >> 16) & 1u)) & 0xffff0000u;
    return ua | ub;
}

__global__ __launch_bounds__(256) void k_partition(
    const int* __restrict__ src, const int* __restrict__ dst, int E,
    int* __restrict__ bcur, unsigned* __restrict__ words, int cap) {
    __shared__ int cnt[256];
    __shared__ int gbase[256];
    int t = threadIdx.x;
    int base = blockIdx.x * (256 * ITEMS);
    cnt[t] = 0;
    __syncthreads();
    unsigned w[ITEMS]; int b[ITEMS], r[ITEMS];
    #pragma unroll
    for (int j = 0; j < ITEMS; ++j) {
        int e = base + j * 256 + t;
        if (e < E) {
            int d = dst[e], s = src[e];
            b[j] = d >> SHIFT;
            w[j] = ((unsigned)s << SHIFT) | (unsigned)(d & (BW_ - 1));
            r[j] = atomicAdd(&cnt[b[j]], 1);     // LDS atomic
        } else b[j] = -1;
    }
    __syncthreads();
    int c = cnt[t];
    gbase[t] = c ? atomicAdd(&bcur[t], c) : 0;
    __syncthreads();
    #pragma unroll
    for (int j = 0; j < ITEMS; ++j) {
        if (b[j] >= 0) {
            int idx = gbase[b[j]] + r[j];
            if (idx < cap)
                words[(size_t)b[j] * cap + idx] = w[j];
        }
    }
}

__global__ __launch_bounds__(512) void k_hist(
    const unsigned* __restrict__ words, const int* __restrict__ bcnt, int cap,
    int* __restrict__ deg, int N) {
    __shared__ int h[BW_];
    int b = blockIdx.x, t = threadIdx.x;
    h[t] = 0;
    __syncthreads();
    int n = min(bcnt[b], cap);
    const unsigned* wb = words + (size_t)b * cap;
    for (int i = t; i < n; i += 512)
        atomicAdd(&h[wb[i] & (BW_ - 1)], 1);
    __syncthreads();
    int node = b * BW_ + t;
    if (node < N) deg[node] = h[t];
}

__global__ __launch_bounds__(512) void k_place(
    const unsigned* __restrict__ words, const int* __restrict__ bcnt, int cap,
    const int* __restrict__ rowptr, int* __restrict__ col, int N) {
    __shared__ int cur[BW_];
    int b = blockIdx.x, t = threadIdx.x;
    int node = b * BW_ + t;
    cur[t] = (node < N) ? rowptr[node] : 0;
    __syncthreads();
    int n = min(bcnt[b], cap);
    const unsigned* wb = words + (size_t)b * cap;
    for (int i = t; i < n; i += 512) {
        unsigned w = wb[i];
        int p = atomicAdd(&cur[w & (BW_ - 1)], 1);
        col[p] = (int)(w >> SHIFT);
    }
}

__global__ void k_scan1(const int* __restrict__ deg, int N,
                        int* __restrict__ rowptr, int* __restrict__ bsum) {
    __shared__ int lds[256];
    int t = threadIdx.x;
    int i = blockIdx.x * 256 + t;
    int v = (i < N) ? deg[i] : 0;
    lds[t] = v; __syncthreads();
    #pragma unroll
    for (int off = 1; off < 256; off <<= 1) {
        int tmp = (t >= off) ? lds[t - off] : 0; __syncthreads();
        lds[t] += tmp; __syncthreads();
    }
    if (i < N) rowptr[i] = lds[t] - v;
    if (t == 255) bsum[blockIdx.x] = lds[255];
}

__global__ void k_scan2(const int* __restrict__ bsum, int nb, int* __restrict__ boff) {
    __shared__ int lds[1024];
    int t = threadIdx.x;
    int v = (t < nb) ? bsum[t] : 0;
    lds[t] = v; __syncthreads();
    #pragma unroll
    for (int off = 1; off < 1024; off <<= 1) {
        int tmp = (t >= off) ? lds[t - off] : 0; __syncthreads();
        lds[t] += tmp; __syncthreads();
    }
    if (t < nb) boff[t] = lds[t] - v;
    if (t == 0) boff[nb] = lds[1023];
}

__global__ void k_scan3(const int* __restrict__ boff, int N, int nb,
                        int* __restrict__ rowptr, const int* __restrict__ deg,
                        float* __restrict__ dinv) {
    int i = blockIdx.x * blockDim.x + threadIdx.x;
    if (i < N) {
        rowptr[i] += boff[i >> 8];
        dinv[i] = rsqrtf((float)deg[i] + 1.0f);
    } else if (i == N) {
        rowptr[N] = boff[nb];
    }
}

// hw1[n] packed: uint f = bf16(dinv*(x*W1[0,2f]+c0)) | bf16(...2f+1)<<16
__global__ void k_layer1(const float* __restrict__ x, const float* __restrict__ delta,
                         const float* __restrict__ W1, const float* __restrict__ dinv,
                         unsigned* __restrict__ hw, int N) {
    int idx = blockIdx.x * blockDim.x + threadIdx.x;
    if (idx >= N * 32) return;
    int n = idx >> 5, f = idx & 31;
    int d0 = 2 * f, d1 = 2 * f + 1;
    float c0 = delta[0] * W1[64 + d0] + delta[1] * W1[128 + d0] +
               delta[2] * W1[192 + d0] + delta[3] * W1[256 + d0];
    float c1 = delta[0] * W1[64 + d1] + delta[1] * W1[128 + d1] +
               delta[2] * W1[192 + d1] + delta[3] * W1[256 + d1];
    float dn = dinv[n], xv = x[n];
    hw[idx] = packbf(dn * fmaf(xv, W1[d0], c0), dn * fmaf(xv, W1[d1], c1));
}

// Gather one <=64-edge chunk, 16 edges per group (8 loads in flight).
__device__ __forceinline__ void gather16(const unsigned* __restrict__ hw,
                                         int s, int cnt, int fb, int half,
                                         float& a0, float& a1) {
    for (int j = 0; j < cnt; j += 16) {
        unsigned v[8]; int e[8];
        #pragma unroll
        for (int g = 0; g < 8; ++g) {
            e[g] = j + 2 * g + half;
            int idx = __shfl(s, min(e[g], cnt - 1));
            v[g] = hw[(size_t)idx * 32 + fb];
        }
        #pragma unroll
        for (int g = 0; g < 8; ++g) {
            unsigned w = (e[g] < cnt) ? v[g] : 0u;
            a0 += blo(w); a1 += bhi(w);
        }
    }
}

// Pure gather + relu + pack: h2 = relu(dinv*agg + b). (R6 structure, GEMM removed.)
__global__ __launch_bounds__(256) void k_agg1(
    const unsigned* __restrict__ hw_in, const int* __restrict__ rowptr,
    const int* __restrict__ col, const float* __restrict__ dinv,
    const float* __restrict__ bias, unsigned* __restrict__ h2u, int N) {
    int lane = threadIdx.x & 63;
    int fb = lane & 31, half = lane >> 5;
    float b0 = bias[2 * fb], b1 = bias[2 * fb + 1];
    int stride = gridDim.x * 4;
    int n = blockIdx.x * 4 + (threadIdx.x >> 6);
    int rs = 0, re = 0;
    if (n < N) { rs = rowptr[n]; re = rowptr[n + 1]; }
    int cnt0 = min(64, re - rs);
    int s = (cnt0 > 0) ? col[rs + min(lane, cnt0 - 1)] : 0;
    while (n < N) {
        int n2 = n + stride;
        int rs2 = 0, re2 = 0;
        if (n2 < N) { rs2 = rowptr[n2]; re2 = rowptr[n2 + 1]; }
        int cnt2 = min(64, re2 - rs2);
        int s2 = (cnt2 > 0) ? col[rs2 + min(lane, cnt2 - 1)] : 0;  // prefetch next
        unsigned sw = hw_in[(size_t)n * 32 + fb];                  // self-loop
        float a0 = 0.f, a1 = 0.f;
        gather16(hw_in, s, cnt0, fb, half, a0, a1);
        for (int base = rs + 64; base < re; base += 64) {          // rare: deg>64
            int cc = min(64, re - base);
            int sx = col[base + min(lane, cc - 1)];
            gather16(hw_in, sx, cc, fb, half, a0, a1);
        }
        a0 += __shfl_xor(a0, 32);
        a1 += __shfl_xor(a1, 32);
        a0 += blo(sw); a1 += bhi(sw);
        float dn = dinv[n];
        float t0 = fmaxf(fmaf(dn, a0, b0), 0.0f);
        float t1 = fmaxf(fmaf(dn, a1, b1), 0.0f);
        if (half == 0) h2u[(size_t)n * 32 + fb] = packbf(t0, t1);
        n = n2; rs = rs2; re = re2; cnt0 = cnt2; s = s2;
    }
}

// Dense hw2 = dinv * (h2 @ W2), bf16 in/out. 8 nodes per wave, rows in VGPRs,
// broadcast via literal-index readlane, W L1 traffic amortized 8x.
__global__ __launch_bounds__(256) void k_gemm64(
    const unsigned* __restrict__ h2u, const float* __restrict__ dinv,
    const float* __restrict__ W, unsigned* __restrict__ hw2, int N) {
    int lane = threadIdx.x & 63, wave = threadIdx.x >> 6;
    int q = lane & 31, h = lane >> 5;
    int nb_stride = gridDim.x * 4 * 8;
    for (int nb = (blockIdx.x * 4 + wave) * 8; nb < N; nb += nb_stride) {
        // u[p]: lanes<32 hold node nb+2p feat-pair q; lanes>=32 node nb+2p+1
        float lo[4], hi[4];
        #pragma unroll
        for (int p = 0; p < 4; ++p) {
            int node = min(nb + 2 * p + h, N - 1);
            unsigned u = h2u[(size_t)node * 32 + q];
            lo[p] = blo(u); hi[p] = bhi(u);
        }
        float o[8];
        #pragma unroll
        for (int m = 0; m < 8; ++m) o[m] = 0.f;
        #pragma unroll
        for (int k = 0; k < 64; ++k) {
            float w = W[k * 64 + lane];          // d = lane; 16KB L1 per 8 nodes
            #pragma unroll
            for (int m = 0; m < 8; ++m) {
                float srcreg = (k & 1) ? hi[m >> 1] : lo[m >> 1];
                float s = __uint_as_float(__builtin_amdgcn_readlane(
                              (int)__float_as_uint(srcreg),
                              (k >> 1) + (m & 1) * 32));
                o[m] = fmaf(s, w, o[m]);
            }
        }
        #pragma unroll
        for (int m = 0; m < 8; ++m) {
            int nn = nb + m;
            if (nn < N) {
                float v = dinv[nn] * o[m];
                float v2 = __shfl_down(v, 1);
                if ((lane & 1) == 0)
                    hw2[(size_t)nn * 32 + (lane >> 1)] = packbf(v, v2);
            }
        }
    }
}

// Gather hw2 + relu + W3 (64x3) reduce -> hw3 float4 (R6 agg_out3 unchanged).
__global__ __launch_bounds__(256, 4) void k_agg2(
    const unsigned* __restrict__ hw_in, const int* __restrict__ rowptr,
    const int* __restrict__ col, const float* __restrict__ dinv,
    const float* __restrict__ bias, const float* __restrict__ W3,
    float4* __restrict__ hw3, int N) {
    int lane = threadIdx.x & 63, wave = threadIdx.x >> 6;
    int fb = lane & 31, half = lane >> 5;
    int d0 = 2 * fb, d1 = 2 * fb + 1;
    float wa0 = W3[d0 * 3 + 0], wa1 = W3[d0 * 3 + 1], wa2 = W3[d0 * 3 + 2];
    float wb0 = W3[d1 * 3 + 0], wb1 = W3[d1 * 3 + 1], wb2 = W3[d1 * 3 + 2];
    float b0 = bias[d0], b1 = bias[d1];
    int stride = gridDim.x * 4;
    int n = blockIdx.x * 4 + wave;
    int rs = 0, re = 0;
    if (n < N) { rs = rowptr[n]; re = rowptr[n + 1]; }
    int cnt0 = min(64, re - rs);
    int s = (cnt0 > 0) ? col[rs + min(lane, cnt0 - 1)] : 0;
    while (n < N) {
        int n2 = n + stride;
        int rs2 = 0, re2 = 0;
        if (n2 < N) { rs2 = rowptr[n2]; re2 = rowptr[n2 + 1]; }
        int cnt2 = min(64, re2 - rs2);
        int s2 = (cnt2 > 0) ? col[rs2 + min(lane, cnt2 - 1)] : 0;
        unsigned sw = hw_in[(size_t)n * 32 + fb];
        float a0 = 0.f, a1 = 0.f;
        gather16(hw_in, s, cnt0, fb, half, a0, a1);
        for (int base = rs + 64; base < re; base += 64) {
            int cc = min(64, re - base);
            int sx = col[base + min(lane, cc - 1)];
            gather16(hw_in, sx, cc, fb, half, a0, a1);
        }
        a0 += __shfl_xor(a0, 32);
        a1 += __shfl_xor(a1, 32);
        a0 += blo(sw); a1 += bhi(sw);
        float dn = dinv[n];
        float t0 = fmaxf(fmaf(dn, a0, b0), 0.0f);
        float t1 = fmaxf(fmaf(dn, a1, b1), 0.0f);
        float p0 = fmaf(t0, wa0, t1 * wb0);
        float p1 = fmaf(t0, wa1, t1 * wb1);
        float p2 = fmaf(t0, wa2, t1 * wb2);
        #pragma unroll
        for (int off = 16; off; off >>= 1) {     // halves identical: reduce 32
            p0 += __shfl_xor(p0, off);
            p1 += __shfl_xor(p1, off);
            p2 += __shfl_xor(p2, off);
        }
        if (lane == 0) hw3[n] = make_float4(dn * p0, dn * p1, dn * p2, 0.f);
        n = n2; rs = rs2; re = re2; cnt0 = cnt2; s = s2;
    }
}

__global__ __launch_bounds__(256) void k_final(
    const float4* __restrict__ hw3, const int* __restrict__ rowptr,
    const int* __restrict__ col, const float* __restrict__ dinv,
    const float* __restrict__ b3, const float* __restrict__ x,
    const float* __restrict__ pos, float* __restrict__ out, int N) {
    int lane = threadIdx.x & 63, wave = threadIdx.x >> 6;
    int n = blockIdx.x * 4 + wave;
    if (n >= N) return;
    int rs = rowptr[n], re = rowptr[n + 1];
    float a0 = 0.f, a1 = 0.f, a2 = 0.f;
    for (int i = rs + lane; i < re; i += 64) {
        float4 v = hw3[col[i]];
        a0 += v.x; a1 += v.y; a2 += v.z;
    }
    #pragma unroll
    for (int off = 32; off; off >>= 1) {
        a0 += __shfl_xor(a0, off);
        a1 += __shfl_xor(a1, off);
        a2 += __shfl_xor(a2, off);
    }
    if (lane == 0) {
        float4 sv = hw3[n];
        a0 += sv.x; a1 += sv.y; a2 += sv.z;
        float dn = dinv[n];
        float o0 = fmaf(dn, a0, b3[0]);
        float o1 = fmaf(dn, a1, b3[1]);
        float o2 = fmaf(dn, a2, b3[2]);
        out[n] = x[n] + o2;
        out[N + 2 * n]     = pos[2 * n]     + o0;
        out[N + 2 * n + 1] = pos[2 * n + 1] + o1;
    }
}

extern "C" void kernel_launch(void* const* d_in, const int* in_sizes, int n_in,
                              void* d_out, int out_size, void* d_ws, size_t ws_size,
                              hipStream_t stream) {
    const float* x     = (const float*)d_in[0];
    const float* pos   = (const float*)d_in[1];
    const float* delta = (const float*)d_in[2];
    const int*   ei    = (const int*)  d_in[3];
    const float* W1    = (const float*)d_in[4];
    const float* b1    = (const float*)d_in[5];
    const float* W2    = (const float*)d_in[6];
    const float* b2    = (const float*)d_in[7];
    const float* W3    = (const float*)d_in[8];
    const float* b3    = (const float*)d_in[9];
    int N = in_sizes[0];
    int E = in_sizes[3] / 2;
    const int* src = ei;
    const int* dst = ei + E;

    char* p = (char*)d_ws;
    auto alloc = [&](size_t bytes) {
        char* r = p; p += (bytes + 255) & ~(size_t)255; return r;
    };
    int*   deg    = (int*)  alloc((size_t)N * 4);
    int*   bcur   = (int*)  alloc(256 * 4);
    int*   rowptr = (int*)  alloc((size_t)(N + 1) * 4);
    int nb1 = (N + 255) / 256;
    int*   bsum   = (int*)  alloc((size_t)nb1 * 4);
    int*   boff   = (int*)  alloc((size_t)(nb1 + 1) * 4);
    float* dinv   = (float*)alloc((size_t)N * 4);
    int*   col    = (int*)  alloc((size_t)E * 4);
    unsigned* hw1 = (unsigned*)alloc((size_t)N * 32 * 4);  // bf16x2 packed
    unsigned* hw2 = (unsigned*)alloc((size_t)N * 32 * 4);

    int B   = (N + BW_ - 1) >> SHIFT;   // 196 buckets for N=100K
    int cap = 2 * (E / B) + 1024;
    size_t wbytes = (size_t)B * cap * 4;                   // ~13.6MB
    size_t h2bytes = (size_t)N * 32 * 4;                   // 12.8MB
    unsigned* words = (unsigned*)alloc(wbytes > h2bytes ? wbytes : h2bytes);
    unsigned* h2u   = words;            // words dead after k_place
    float4*   hw3   = (float4*)hw1;     // hw1 dead after k_agg1

    int npb = (E + (256 * ITEMS) - 1) / (256 * ITEMS);

    hipMemsetAsync(bcur, 0, 256 * 4, stream);
    k_partition<<<npb, 256, 0, stream>>>(src, dst, E, bcur, words, cap);
    k_hist<<<B, 512, 0, stream>>>(words, bcur, cap, deg, N);
    k_scan1<<<nb1, 256, 0, stream>>>(deg, N, rowptr, bsum);
    k_scan2<<<1, 1024, 0, stream>>>(bsum, nb1, boff);
    k_scan3<<<(N + 256) / 256, 256, 0, stream>>>(boff, N, nb1, rowptr, deg, dinv);
    k_place<<<B, 512, 0, stream>>>(words, bcur, cap, rowptr, col, N);
    k_layer1<<<(N * 32 + 255) / 256, 256, 0, stream>>>(x, delta, W1, dinv, hw1, N);
    k_agg1<<<2048, 256, 0, stream>>>(hw1, rowptr, col, dinv, b1, h2u, N);
    k_gemm64<<<1024, 256, 0, stream>>>(h2u, dinv, W2, hw2, N);
    k_agg2<<<2048, 256, 0, stream>>>(hw2, rowptr, col, dinv, b2, W3, hw3, N);
    k_final<<<(N + 3) / 4, 256, 0, stream>>>(hw3, rowptr, col, dinv, b3, x, pos,
                                             (float*)d_out, N);
}